// Round 4
// baseline (28299.979 us; speedup 1.0000x reference)
//
#include <hip/hip_runtime.h>
#include <math.h>

// DARTS recurrent cell on MI355X — single persistent cooperative kernel.
// 4 independent row-tile pipelines (16 rows each) x 64 col-group WGs.
// Cross-WG sync: per-(tensor,row-tile) device-scope counters, release/acquire.
// GEMMs: fp16 2-limb split MFMA (x = l0 + l1/2048), weights pre-swizzled to
// fragment order; published states stored as planar limb fragments.

typedef __attribute__((ext_vector_type(8))) _Float16 half8;
typedef __attribute__((ext_vector_type(4))) float f32x4;

#define NH 1024
#define SCALE 2048.f
#define INVS  (1.f/2048.f)
#define WF_BYTES   83886080ull     // 41,943,040 ushorts
#define AFRAG_RT   65536           // bytes per row-tile per tensor
#define AFRAG_T    262144          // bytes per tensor (4 rt)
#define T_STEPS    256

__device__ __forceinline__ float sigf(float x){ return 1.f/(1.f+__expf(-x)); }
__device__ __forceinline__ void limbs2(float x, _Float16& a, _Float16& b){
    a = (_Float16)x; b = (_Float16)((x - (float)a)*SCALE);
}

// ---------------- weight pre-swizzle (fragment order, 2 limbs) ---------------
struct Pre { const float* W0; const float* Ws; unsigned short* wf; };

__global__ __launch_bounds__(256) void preconv(Pre d) {
    int gid  = blockIdx.x * 4 + (threadIdx.x >> 6);
    int lane = threadIdx.x & 63;
    const float* W; unsigned short* dst; int nks, cg, ks;
    if (gid < 8192) {                       // W0: 128 cg x 64 ks
        W = d.W0; dst = d.wf; nks = 64; cg = gid >> 6; ks = gid & 63;
    } else {                                // Ws[m]: 128 cg x 32 ks
        int g = gid - 8192; int mm = g >> 12; int wi = g & 4095;
        W   = d.Ws + (size_t)mm * (1024 * 2048);
        dst = d.wf + 8388608ull + (size_t)mm * 4194304ull;
        nks = 32; cg = wi >> 5; ks = wi & 31;
    }
    int c  = cg * 16 + (lane & 15);
    int kb = ks * 32 + (lane >> 4) * 8;
    half8 h0, h1;
    #pragma unroll
    for (int j = 0; j < 8; ++j) {
        _Float16 p, q; limbs2(W[(size_t)(kb + j) * 2048 + c], p, q);
        h0[j] = p; h1[j] = q;
    }
    unsigned short* o = dst + ((size_t)cg * nks + ks) * 1024 + lane * 8;
    *(half8*)o         = h0;
    *(half8*)(o + 512) = h1;
}

// -------- init: hidden -> H frag planes; zero sync counters ------------------
__global__ __launch_bounds__(256) void initk(const float* hidden, char* afrag, int* flags) {
    int gid = blockIdx.x * 256 + threadIdx.x;        // 0..16383
    if (gid < 512) flags[gid] = 0;
    #pragma unroll
    for (int e = 0; e < 4; ++e) {
        int i = gid * 4 + e;                          // 0..65535
        int row = i >> 10, col = i & 1023;
        int rt = row >> 4, rowf = row & 15;
        int ksp = col >> 5, kin = col & 31;
        int lanep = (kin >> 3) * 16 + rowf;
        size_t off = (size_t)rt * AFRAG_RT + ((size_t)ksp * 128 + lanep) * 16 + (kin & 7) * 2;
        _Float16 u0, u1; limbs2(hidden[i], u0, u1);
        *(_Float16*)(afrag + off)        = u0;
        *(_Float16*)(afrag + off + 1024) = u1;
    }
}

// ------------------------------ device helpers -------------------------------
__device__ __forceinline__ void aload(const char* fa, int ks, int lane, half8& a0, half8& a1) {
    const char* p = fa + ((size_t)ks * 128 + lane) * 16;
    a0 = *(const half8*)p;
    a1 = *(const half8*)(p + 1024);
}

__device__ __forceinline__ void wload_raw(const float* W, int c, int kb,
        half8& w0c, half8& w1c, half8& w0h, half8& w1h) {
    #pragma unroll
    for (int j = 0; j < 8; ++j) {
        _Float16 p, q;
        limbs2(W[(size_t)(kb + j) * 2048 + c], p, q);        w0c[j] = p; w1c[j] = q;
        limbs2(W[(size_t)(kb + j) * 2048 + c + 1024], p, q); w0h[j] = p; w1h[j] = q;
    }
}

template<int PRE>
__device__ __forceinline__ void unitW(const unsigned short* wf, const float* wraw,
        int cg, int nks, int ks, int lane8, int c, int kb,
        half8 a0, half8 a1, f32x4& c0, f32x4& c1, f32x4& h0, f32x4& h1) {
    half8 w0c, w1c, w0h, w1h;
    if (PRE) {
        const unsigned short* pc = wf + ((size_t)cg * nks + ks) * 1024 + lane8;
        const unsigned short* ph = wf + ((size_t)(cg + 64) * nks + ks) * 1024 + lane8;
        w0c = *(const half8*)pc; w1c = *(const half8*)(pc + 512);
        w0h = *(const half8*)ph; w1h = *(const half8*)(ph + 512);
    } else {
        wload_raw(wraw, c, kb, w0c, w1c, w0h, w1h);
    }
    c0 = __builtin_amdgcn_mfma_f32_16x16x32_f16(a0, w0c, c0, 0, 0, 0);
    c1 = __builtin_amdgcn_mfma_f32_16x16x32_f16(a0, w1c, c1, 0, 0, 0);
    c1 = __builtin_amdgcn_mfma_f32_16x16x32_f16(a1, w0c, c1, 0, 0, 0);
    h0 = __builtin_amdgcn_mfma_f32_16x16x32_f16(a0, w0h, h0, 0, 0, 0);
    h1 = __builtin_amdgcn_mfma_f32_16x16x32_f16(a0, w1h, h1, 0, 0, 0);
    h1 = __builtin_amdgcn_mfma_f32_16x16x32_f16(a1, w0h, h1, 0, 0, 0);
}

__device__ __forceinline__ void rwrite(float* red, int wave, int u, int lane,
        f32x4 c0, f32x4 c1, f32x4 h0, f32x4 h1) {
    float* b = red + (size_t)(wave * 3 + u) * 512;
    #pragma unroll
    for (int r = 0; r < 4; ++r) {
        b[lane * 4 + r]       = c0[r] + c1[r] * INVS;
        b[256 + lane * 4 + r] = h0[r] + h1[r] * INVS;
    }
}

__device__ __forceinline__ void rsum(const float* red, int u, int idx, float& cs, float& hs) {
    float c = 0.f, h = 0.f;
    #pragma unroll
    for (int w = 0; w < 8; ++w) {
        c += red[(size_t)(w * 3 + u) * 512 + idx];
        h += red[(size_t)(w * 3 + u) * 512 + 256 + idx];
    }
    cs = c; hs = h;
}

__device__ __forceinline__ void fstore(char* fa, int offp, float v) {
    _Float16 u0, u1; limbs2(v, u0, u1);
    *(_Float16*)(fa + offp)        = u0;
    *(_Float16*)(fa + offp + 1024) = u1;
}

__device__ __forceinline__ void waitcnt_ge(int* c, int tgt) {
    while (__hip_atomic_load(c, __ATOMIC_RELAXED, __HIP_MEMORY_SCOPE_AGENT) < tgt)
        __builtin_amdgcn_s_sleep(1);
    (void)__hip_atomic_load(c, __ATOMIC_ACQUIRE, __HIP_MEMORY_SCOPE_AGENT);
}

__device__ __forceinline__ void publish(int* c) {
    __hip_atomic_fetch_add(c, 1, __ATOMIC_RELEASE, __HIP_MEMORY_SCOPE_AGENT);
}

// ------------------------------ persistent kernel ----------------------------
struct PK {
    const float* x; const float* hidden;
    const unsigned short* wf;
    const float* W0; const float* Ws;
    char* afrag; int* flags; float* out;
};

template<int PRE>
__global__ __launch_bounds__(512, 2) void persist(PK p) {
    __shared__ float red[8 * 3 * 512];          // 48 KB reduce arena

    const int tid  = threadIdx.x;
    const int wave = tid >> 6, lane = tid & 63;
    const int l15 = lane & 15, lg = lane >> 4;
    const int lane8 = lane * 8, lg8 = lg * 8;
    const int bx = blockIdx.x;
    const int cg = (bx & 7) * 8 + ((bx >> 3) & 7);   // XCD-swizzle: same cg -> same XCD
    const int rt = bx >> 6;
    const int cglob = cg * 16 + l15;                 // raw-W column (fallback)

    // fragment buffers (per tensor, this row-tile): 0:H 1:S0 2:S1 3:S2 4:S3 5:S5
    char* FA[6];
    #pragma unroll
    for (int i = 0; i < 6; ++i) FA[i] = p.afrag + (size_t)i * AFRAG_T + (size_t)rt * AFRAG_RT;

    const unsigned short* wf0 = p.wf;
    const unsigned short* wfs[8];
    const float* Wr[8];
    #pragma unroll
    for (int i = 0; i < 8; ++i) {
        wfs[i] = PRE ? p.wf + 8388608ull + (size_t)i * 4194304ull : (const unsigned short*)0;
        Wr[i]  = p.Ws + (size_t)i * 2097152;
    }
    #define CNT(tn) (p.flags + ((tn) * 4 + rt) * 16)

    // epilogue-thread fixed position (tid < 256)
    const int rowf = tid >> 4, colf = tid & 15;
    const size_t opos = (size_t)(rt * 16 + rowf) * NH + cg * 16 + colf;
    const int idx = colf * 4 + (rowf >> 2) * 64 + (rowf & 3);
    int offp;
    {
        int col = cg * 16 + colf;
        int ksp = col >> 5, kin = col & 31;
        int lanep = (kin >> 3) * 16 + rowf;
        offp = (ksp * 128 + lanep) * 16 + (kin & 7) * 2;
    }
    float hprev = 0.f, s0v = 0.f, s1v = 0.f, s2v = 0.f, s3v = 0.f, s5v = 0.f, runsum = 0.f;
    if (tid < 256) hprev = p.hidden[opos];

    const int xrow = rt * 16 + l15;

    for (int t = 0; t < T_STEPS; ++t) {
        const float* xt = p.x + (size_t)t * 65536;

        // ================= L1: s0 = comb(h, [x|h] @ W0) =================
        if (tid == 448) waitcnt_ge(CNT(0), 64 * t);
        __syncthreads();
        {
            f32x4 c0 = {}, c1 = {}, h0 = {}, h1 = {};
            #pragma unroll
            for (int i = 0; i < 8; ++i) {
                const int ks = wave * 8 + i;
                half8 a0, a1;
                if (ks < 32) {
                    const float* xp = xt + (size_t)xrow * NH + ks * 32 + lg8;
                    float4 v0 = *(const float4*)xp, v1 = *(const float4*)(xp + 4);
                    float fv[8] = {v0.x, v0.y, v0.z, v0.w, v1.x, v1.y, v1.z, v1.w};
                    #pragma unroll
                    for (int j = 0; j < 8; ++j) { _Float16 u, w2; limbs2(fv[j], u, w2); a0[j] = u; a1[j] = w2; }
                } else {
                    aload(FA[0], ks - 32, lane, a0, a1);
                }
                unitW<PRE>(wf0, p.W0, cg, 64, ks, lane8, cglob, ks * 32 + lg8, a0, a1, c0, c1, h0, h1);
            }
            rwrite(red, wave, 0, lane, c0, c1, h0, h1);
        }
        __syncthreads();
        if (tid < 256) {
            float cs, hs; rsum(red, 0, idx, cs, hs);
            s0v = hprev + sigf(cs) * (tanhf(hs) - hprev);
            fstore(FA[1], offp, s0v);
        }
        __syncthreads();
        if (tid == 0) publish(CNT(1));

        // ================= L2: s1 = comb(s0, s0 @ Ws0) =================
        if (tid == 448) waitcnt_ge(CNT(1), 64 * (t + 1));
        __syncthreads();
        {
            f32x4 c0 = {}, c1 = {}, h0 = {}, h1 = {};
            #pragma unroll
            for (int i = 0; i < 4; ++i) {
                const int ks = wave * 4 + i;
                half8 a0, a1; aload(FA[1], ks, lane, a0, a1);
                unitW<PRE>(wfs[0], Wr[0], cg, 32, ks, lane8, cglob, ks * 32 + lg8, a0, a1, c0, c1, h0, h1);
            }
            rwrite(red, wave, 0, lane, c0, c1, h0, h1);
        }
        __syncthreads();
        if (tid < 256) {
            float cs, hs; rsum(red, 0, idx, cs, hs);
            s1v = s0v + sigf(cs) * (sigf(hs) - s0v);
            fstore(FA[2], offp, s1v);
            runsum = s1v;
        }
        __syncthreads();
        if (tid == 0) publish(CNT(2));

        // ================= L3: s2,s3,s4 from s1 (Ws1..3) =================
        if (tid == 448) waitcnt_ge(CNT(2), 64 * (t + 1));
        __syncthreads();
        {
            f32x4 ac0 = {}, ac1 = {}, ah0 = {}, ah1 = {};
            f32x4 bc0 = {}, bc1 = {}, bh0 = {}, bh1 = {};
            f32x4 cc0 = {}, cc1 = {}, ch0 = {}, ch1 = {};
            #pragma unroll
            for (int i = 0; i < 4; ++i) {
                const int ks = wave * 4 + i;
                const int kb = ks * 32 + lg8;
                half8 a0, a1; aload(FA[2], ks, lane, a0, a1);
                unitW<PRE>(wfs[1], Wr[1], cg, 32, ks, lane8, cglob, kb, a0, a1, ac0, ac1, ah0, ah1);
                unitW<PRE>(wfs[2], Wr[2], cg, 32, ks, lane8, cglob, kb, a0, a1, bc0, bc1, bh0, bh1);
                unitW<PRE>(wfs[3], Wr[3], cg, 32, ks, lane8, cglob, kb, a0, a1, cc0, cc1, ch0, ch1);
            }
            rwrite(red, wave, 0, lane, ac0, ac1, ah0, ah1);
            rwrite(red, wave, 1, lane, bc0, bc1, bh0, bh1);
            rwrite(red, wave, 2, lane, cc0, cc1, ch0, ch1);
        }
        __syncthreads();
        if (tid < 256) {
            float cs, hs;
            rsum(red, 0, idx, cs, hs); s2v = s1v + sigf(cs) * (fmaxf(hs, 0.f) - s1v);
            rsum(red, 1, idx, cs, hs); s3v = s1v + sigf(cs) * (fmaxf(hs, 0.f) - s1v);
            rsum(red, 2, idx, cs, hs); float s4v = s1v + sigf(cs) * (hs - s1v);
            fstore(FA[3], offp, s2v);
            fstore(FA[4], offp, s3v);
            runsum += s2v + s3v + s4v;
        }
        __syncthreads();
        if (tid == 0) { publish(CNT(3)); publish(CNT(4)); }

        // ================= L4: s5 = comb(s2,Ws4), s7 = comb(s3,Ws6) ======
        if (tid == 448) { waitcnt_ge(CNT(3), 64 * (t + 1)); waitcnt_ge(CNT(4), 64 * (t + 1)); }
        __syncthreads();
        {
            f32x4 ac0 = {}, ac1 = {}, ah0 = {}, ah1 = {};
            f32x4 bc0 = {}, bc1 = {}, bh0 = {}, bh1 = {};
            #pragma unroll
            for (int i = 0; i < 4; ++i) {
                const int ks = wave * 4 + i;
                const int kb = ks * 32 + lg8;
                half8 a0, a1;
                aload(FA[3], ks, lane, a0, a1);
                unitW<PRE>(wfs[4], Wr[4], cg, 32, ks, lane8, cglob, kb, a0, a1, ac0, ac1, ah0, ah1);
                aload(FA[4], ks, lane, a0, a1);
                unitW<PRE>(wfs[6], Wr[6], cg, 32, ks, lane8, cglob, kb, a0, a1, bc0, bc1, bh0, bh1);
            }
            rwrite(red, wave, 0, lane, ac0, ac1, ah0, ah1);
            rwrite(red, wave, 1, lane, bc0, bc1, bh0, bh1);
        }
        __syncthreads();
        float s7v = 0.f;
        if (tid < 256) {
            float cs, hs;
            rsum(red, 0, idx, cs, hs); s5v = s2v + sigf(cs) * (tanhf(hs) - s2v);
            rsum(red, 1, idx, cs, hs); s7v = s3v + sigf(cs) * (tanhf(hs) - s3v);
            fstore(FA[5], offp, s5v);
            runsum += s5v + s7v;
        }
        __syncthreads();
        if (tid == 0) publish(CNT(5));

        // ================= L5: s6,s8 from s5 + mean -> out[t] ============
        if (tid == 448) waitcnt_ge(CNT(5), 64 * (t + 1));
        __syncthreads();
        {
            f32x4 ac0 = {}, ac1 = {}, ah0 = {}, ah1 = {};
            f32x4 bc0 = {}, bc1 = {}, bh0 = {}, bh1 = {};
            #pragma unroll
            for (int i = 0; i < 4; ++i) {
                const int ks = wave * 4 + i;
                const int kb = ks * 32 + lg8;
                half8 a0, a1; aload(FA[5], ks, lane, a0, a1);
                unitW<PRE>(wfs[5], Wr[5], cg, 32, ks, lane8, cglob, kb, a0, a1, ac0, ac1, ah0, ah1);
                unitW<PRE>(wfs[7], Wr[7], cg, 32, ks, lane8, cglob, kb, a0, a1, bc0, bc1, bh0, bh1);
            }
            rwrite(red, wave, 0, lane, ac0, ac1, ah0, ah1);
            rwrite(red, wave, 1, lane, bc0, bc1, bh0, bh1);
        }
        __syncthreads();
        if (tid < 256) {
            float cs, hs;
            rsum(red, 0, idx, cs, hs); float s6 = s5v + sigf(cs) * (sigf(hs) - s5v);
            rsum(red, 1, idx, cs, hs); float s8 = s5v + sigf(cs) * (fmaxf(hs, 0.f) - s5v);
            float v = 0.125f * (runsum + s6 + s8);
            p.out[(size_t)t * 65536 + opos] = v;
            fstore(FA[0], offp, v);
            hprev = v;
        }
        __syncthreads();
        if (tid == 0) publish(CNT(0));
    }
    #undef CNT
}

// ---------------------------------- host -------------------------------------
extern "C" void kernel_launch(void* const* d_in, const int* in_sizes, int n_in,
                              void* d_out, int out_size, void* d_ws, size_t ws_size,
                              hipStream_t stream) {
    (void)in_sizes; (void)n_in; (void)out_size;
    const float* inputs = (const float*)d_in[0];   // [256][64][1024]
    const float* hidden = (const float*)d_in[1];   // [1][64][1024]
    const float* W0     = (const float*)d_in[2];   // [2048][2048]
    const float* Ws     = (const float*)d_in[3];   // [8][1024][2048]
    float* out = (float*)d_out;

    char* base = (char*)d_ws;
    const size_t NEED_PRE = WF_BYTES + 6ull * AFRAG_T + 4096;
    const bool pre = ws_size >= NEED_PRE;

    unsigned short* wf = (unsigned short*)base;
    char* afrag = pre ? base + WF_BYTES : base;
    int*  flags = (int*)(afrag + 6ull * AFRAG_T);

    initk<<<64, 256, 0, stream>>>(hidden, afrag, flags);
    if (pre) preconv<<<10240, 256, 0, stream>>>(Pre{W0, Ws, wf});

    PK pk{inputs, hidden, pre ? wf : (const unsigned short*)0, W0, Ws, afrag, flags, out};

    if (pre) {
        auto fn = persist<1>;
        void* args[] = {&pk};
        if (hipLaunchCooperativeKernel((void*)fn, dim3(256), dim3(512), args, 0, stream) != hipSuccess)
            persist<1><<<256, 512, 0, stream>>>(pk);
    } else {
        auto fn = persist<0>;
        void* args[] = {&pk};
        if (hipLaunchCooperativeKernel((void*)fn, dim3(256), dim3(512), args, 0, stream) != hipSuccess)
            persist<0><<<256, 512, 0, stream>>>(pk);
    }
}

// Round 5
// 23806.573 us; speedup vs baseline: 1.1887x; 1.1887x over previous
//
#include <hip/hip_runtime.h>
#include <math.h>

// DARTS recurrent cell on MI355X — persistent cooperative kernel, v5.
// Fixes vs v4 (28 ms, FETCH=68.7 MB/step = weights re-fetched from HBM):
//  - ONE acquire (L2-invalidate) per step (at L1), not per phase: weights/A-frags
//    are L2-served within a step; FA staleness handled by the per-step acquire.
//  - Per-producer flag array (store-release), wave-parallel 64-lane poll: no
//    single-counter RMW contention.
//  - W0h lives in a 128 KB LDS slab (loaded once): L1 phase reads no global W.
//  - Non-temporal loads for single-use streams (W0x, Ws3..7).

typedef __attribute__((ext_vector_type(8))) _Float16 half8;
typedef __attribute__((ext_vector_type(4))) float f32x4;
typedef __attribute__((ext_vector_type(4))) unsigned int u32x4;

#define NH 1024
#define SCALE 2048.f
#define INVS  (1.f/2048.f)
#define WF_BYTES 83886080ull
#define FA_BYTES 1572864ull        // 6 tensors x 4 rt x 64 KB
#define T_STEPS  256

__device__ __forceinline__ float sigf(float x){ return 1.f/(1.f+__expf(-x)); }
__device__ __forceinline__ void limbs2(float x, _Float16& a, _Float16& b){
    a = (_Float16)x; b = (_Float16)((x - (float)a)*SCALE);
}

// ---------------- weight pre-swizzle (identical to v4, proven) ---------------
struct Pre { const float* W0; const float* Ws; unsigned short* wf; };

__global__ __launch_bounds__(256) void preconv(Pre d) {
    int gid  = blockIdx.x * 4 + (threadIdx.x >> 6);
    int lane = threadIdx.x & 63;
    const float* W; unsigned short* dst; int nks, cg, ks;
    if (gid < 8192) {
        W = d.W0; dst = d.wf; nks = 64; cg = gid >> 6; ks = gid & 63;
    } else {
        int g = gid - 8192; int mm = g >> 12; int wi = g & 4095;
        W   = d.Ws + (size_t)mm * (1024 * 2048);
        dst = d.wf + 8388608ull + (size_t)mm * 4194304ull;
        nks = 32; cg = wi >> 5; ks = wi & 31;
    }
    int c  = cg * 16 + (lane & 15);
    int kb = ks * 32 + (lane >> 4) * 8;
    half8 h0, h1;
    #pragma unroll
    for (int j = 0; j < 8; ++j) {
        _Float16 p, q; limbs2(W[(size_t)(kb + j) * 2048 + c], p, q);
        h0[j] = p; h1[j] = q;
    }
    unsigned short* o = dst + ((size_t)cg * nks + ks) * 1024 + lane * 8;
    *(half8*)o         = h0;
    *(half8*)(o + 512) = h1;
}

// -------- init: hidden -> H frag planes; flag array init ---------------------
__global__ __launch_bounds__(256) void initk(const float* hidden, char* fa, unsigned* flags) {
    int gid = blockIdx.x * 256 + threadIdx.x;        // 0..16383
    if (gid < 1536) flags[gid] = (gid < 256) ? 1u : 0u;   // H published once
    #pragma unroll
    for (int e = 0; e < 4; ++e) {
        int i = gid * 4 + e;
        int row = i >> 10, col = i & 1023;
        int rt = row >> 4, rowf = row & 15;
        int ksp = col >> 5, kin = col & 31;
        int lanep = (kin >> 3) * 16 + rowf;
        size_t off = (size_t)rt * 65536 + ((size_t)ksp * 128 + lanep) * 16 + (kin & 7) * 2;
        _Float16 u0, u1; limbs2(hidden[i], u0, u1);
        *(_Float16*)(fa + off)        = u0;
        *(_Float16*)(fa + off + 1024) = u1;
    }
}

// ------------------------------ device helpers -------------------------------
__device__ __forceinline__ void aload(const char* fa, int ks, int lane, half8& a0, half8& a1) {
    const char* p = fa + ((size_t)ks * 128 + lane) * 16;
    a0 = *(const half8*)p;
    a1 = *(const half8*)(p + 1024);
}
template<int NT>
__device__ __forceinline__ half8 ldw(const unsigned short* p) {
    if constexpr (NT) {
        u32x4 v = __builtin_nontemporal_load((const u32x4*)p);
        return __builtin_bit_cast(half8, v);
    }
    return *(const half8*)p;
}
__device__ __forceinline__ void mfma6(half8 a0, half8 a1, half8 w0, half8 w1,
                                      f32x4& x0, f32x4& x1) {
    x0 = __builtin_amdgcn_mfma_f32_16x16x32_f16(a0, w0, x0, 0, 0, 0);
    x1 = __builtin_amdgcn_mfma_f32_16x16x32_f16(a0, w1, x1, 0, 0, 0);
    x1 = __builtin_amdgcn_mfma_f32_16x16x32_f16(a1, w0, x1, 0, 0, 0);
}
__device__ __forceinline__ void rwrite1(float* arena, int wave, int lane,
        f32x4 c0, f32x4 c1, f32x4 h0, f32x4 h1) {
    float* b = arena + wave * 512;
    #pragma unroll
    for (int r = 0; r < 4; ++r) {
        b[lane * 4 + r]       = c0[r] + c1[r] * INVS;
        b[256 + lane * 4 + r] = h0[r] + h1[r] * INVS;
    }
}
__device__ __forceinline__ void rsum1(const float* arena, int idx, float& cs, float& hs) {
    float c = 0.f, h = 0.f;
    #pragma unroll
    for (int w = 0; w < 8; ++w) {
        c += arena[w * 512 + idx];
        h += arena[w * 512 + 256 + idx];
    }
    cs = c; hs = h;
}
__device__ __forceinline__ void fstore(char* fa, int offp, float v) {
    _Float16 u0, u1; limbs2(v, u0, u1);
    *(_Float16*)(fa + offp)        = u0;
    *(_Float16*)(fa + offp + 1024) = u1;
}
template<int ACQ>
__device__ __forceinline__ void pollw(unsigned* f, unsigned tgt, int lane) {
    unsigned v = __hip_atomic_load(f + lane, __ATOMIC_RELAXED, __HIP_MEMORY_SCOPE_AGENT);
    while (__ballot(v < tgt)) {
        __builtin_amdgcn_s_sleep(1);
        v = __hip_atomic_load(f + lane, __ATOMIC_RELAXED, __HIP_MEMORY_SCOPE_AGENT);
    }
    if (ACQ)
        (void)__hip_atomic_load(f, __ATOMIC_ACQUIRE, __HIP_MEMORY_SCOPE_AGENT);
}
__device__ __forceinline__ void publish(unsigned* slot, unsigned v) {
    __hip_atomic_store(slot, v, __ATOMIC_RELEASE, __HIP_MEMORY_SCOPE_AGENT);
}

// ------------------------------ persistent kernel ----------------------------
struct PK {
    const float* x; const float* hidden;
    const unsigned short* wf;
    char* fa; unsigned* flags; float* out;
};

__global__ __launch_bounds__(512, 2) void persist(PK p) {
    __shared__ unsigned short slab[65536];   // 128 KB: W0h frags (c:0-31, h:32-63)
    __shared__ float arena[4096];            // 16 KB reduce arena

    const int tid  = threadIdx.x;
    const int wave = tid >> 6, lane = tid & 63;
    const int l15 = lane & 15, lg = lane >> 4;
    const int lane8 = lane * 8, lg8 = lg * 8;
    const int bx = blockIdx.x;
    const int cg = (bx & 7) * 8 + ((bx >> 3) & 7);   // same cg set -> same XCD
    const int rt = bx >> 6;

    const unsigned short* wf0 = p.wf;
    const unsigned short* wfs[8];
    #pragma unroll
    for (int i = 0; i < 8; ++i) wfs[i] = p.wf + 8388608ull + (size_t)i * 4194304ull;

    char* FAH  = p.fa + (size_t)(0 * 4 + rt) * 65536;
    char* FAS0 = p.fa + (size_t)(1 * 4 + rt) * 65536;
    char* FAS1 = p.fa + (size_t)(2 * 4 + rt) * 65536;
    char* FAS2 = p.fa + (size_t)(3 * 4 + rt) * 65536;
    char* FAS3 = p.fa + (size_t)(4 * 4 + rt) * 65536;
    char* FAS5 = p.fa + (size_t)(5 * 4 + rt) * 65536;
    #define FLG(tn) (p.flags + ((tn) * 4 + rt) * 64)

    // ---- fill W0h LDS slab (once) ----
    {
        const u32x4* sc = (const u32x4*)(wf0 + ((size_t)cg * 64 + 32) * 1024);
        const u32x4* sh = (const u32x4*)(wf0 + ((size_t)(cg + 64) * 64 + 32) * 1024);
        u32x4* dst = (u32x4*)slab;
        for (int i = tid; i < 4096; i += 512) { dst[i] = sc[i]; dst[4096 + i] = sh[i]; }
    }

    // epilogue-thread fixed position (tid < 256)
    const int rowf = tid >> 4, colf = tid & 15;
    const size_t opos = (size_t)(rt * 16 + rowf) * NH + cg * 16 + colf;
    const int idx = colf * 4 + (rowf >> 2) * 64 + (rowf & 3);
    int offp;
    {
        int col = cg * 16 + colf;
        int ksp = col >> 5, kin = col & 31;
        int lanep = (kin >> 3) * 16 + rowf;
        offp = (ksp * 128 + lanep) * 16 + (kin & 7) * 2;
    }
    float hprev = 0.f, s0v = 0.f, s1v = 0.f, s2v = 0.f, s3v = 0.f, s5v = 0.f, runsum = 0.f;
    if (tid < 256) hprev = p.hidden[opos];
    const int xrow = rt * 16 + l15;
    __syncthreads();

    for (int t = 0; t < T_STEPS; ++t) {
        const float* xt = p.x + (size_t)t * 65536;

        // ========== L1: s0 = comb(h, [x|h] @ W0)  (acquire: 1 per step) ======
        if (wave == 7) pollw<1>(FLG(0), t + 1, lane);
        __syncthreads();
        {
            f32x4 c0 = {}, c1 = {}, h0 = {}, h1 = {};
            #pragma unroll
            for (int i = 0; i < 8; ++i) {
                const int ks = wave * 8 + i;
                half8 a0, a1, w0c, w1c, w0h, w1h;
                if (ks < 32) {                          // x-half: convert + NT W0x
                    const float* xp = xt + (size_t)xrow * NH + ks * 32 + lg8;
                    float4 v0 = *(const float4*)xp, v1 = *(const float4*)(xp + 4);
                    float fv[8] = {v0.x, v0.y, v0.z, v0.w, v1.x, v1.y, v1.z, v1.w};
                    #pragma unroll
                    for (int j = 0; j < 8; ++j) { _Float16 u, w2; limbs2(fv[j], u, w2); a0[j] = u; a1[j] = w2; }
                    const unsigned short* pc = wf0 + ((size_t)cg * 64 + ks) * 1024 + lane8;
                    const unsigned short* ph = wf0 + ((size_t)(cg + 64) * 64 + ks) * 1024 + lane8;
                    w0c = ldw<1>(pc); w1c = ldw<1>(pc + 512);
                    w0h = ldw<1>(ph); w1h = ldw<1>(ph + 512);
                } else {                                // h-half: FA + LDS slab
                    aload(FAH, ks - 32, lane, a0, a1);
                    const unsigned short* pc = &slab[(ks - 32) * 1024 + lane8];
                    const unsigned short* ph = &slab[(ks) * 1024 + lane8];
                    w0c = *(const half8*)pc; w1c = *(const half8*)(pc + 512);
                    w0h = *(const half8*)ph; w1h = *(const half8*)(ph + 512);
                }
                mfma6(a0, a1, w0c, w1c, c0, c1);
                mfma6(a0, a1, w0h, w1h, h0, h1);
            }
            rwrite1(arena, wave, lane, c0, c1, h0, h1);
        }
        __syncthreads();
        if (tid < 256) {
            float cs, hs; rsum1(arena, idx, cs, hs);
            s0v = hprev + sigf(cs) * (tanhf(hs) - hprev);
            fstore(FAS0, offp, s0v);
        }
        __syncthreads();
        if (tid == 0) publish(FLG(1) + cg, t + 1);

        // ========== L2: s1 = comb(s0, s0 @ Ws0)  (Ws0 resident) ==============
        if (wave == 7) pollw<0>(FLG(1), t + 1, lane);
        __syncthreads();
        {
            f32x4 c0 = {}, c1 = {}, h0 = {}, h1 = {};
            #pragma unroll
            for (int i = 0; i < 4; ++i) {
                const int ks = wave * 4 + i;
                half8 a0, a1; aload(FAS0, ks, lane, a0, a1);
                const unsigned short* pc = wfs[0] + ((size_t)cg * 32 + ks) * 1024 + lane8;
                const unsigned short* ph = wfs[0] + ((size_t)(cg + 64) * 32 + ks) * 1024 + lane8;
                mfma6(a0, a1, ldw<0>(pc), ldw<0>(pc + 512), c0, c1);
                mfma6(a0, a1, ldw<0>(ph), ldw<0>(ph + 512), h0, h1);
            }
            rwrite1(arena, wave, lane, c0, c1, h0, h1);
        }
        __syncthreads();
        if (tid < 256) {
            float cs, hs; rsum1(arena, idx, cs, hs);
            s1v = s0v + sigf(cs) * (sigf(hs) - s0v);
            fstore(FAS1, offp, s1v);
            runsum = s1v;
        }
        __syncthreads();
        if (tid == 0) publish(FLG(2) + cg, t + 1);

        // ========== L3: s2,s3,s4 from s1 (Ws1,Ws2 resident; Ws3 NT) ==========
        if (wave == 7) pollw<0>(FLG(2), t + 1, lane);
        __syncthreads();
        f32x4 ac0 = {}, ac1 = {}, ah0 = {}, ah1 = {};
        f32x4 bc0 = {}, bc1 = {}, bh0 = {}, bh1 = {};
        f32x4 cc0 = {}, cc1 = {}, ch0 = {}, ch1 = {};
        #pragma unroll
        for (int i = 0; i < 4; ++i) {
            const int ks = wave * 4 + i;
            half8 a0, a1; aload(FAS1, ks, lane, a0, a1);
            const size_t oc = ((size_t)cg * 32 + ks) * 1024 + lane8;
            const size_t oh = ((size_t)(cg + 64) * 32 + ks) * 1024 + lane8;
            mfma6(a0, a1, ldw<0>(wfs[1] + oc), ldw<0>(wfs[1] + oc + 512), ac0, ac1);
            mfma6(a0, a1, ldw<0>(wfs[1] + oh), ldw<0>(wfs[1] + oh + 512), ah0, ah1);
            mfma6(a0, a1, ldw<0>(wfs[2] + oc), ldw<0>(wfs[2] + oc + 512), bc0, bc1);
            mfma6(a0, a1, ldw<0>(wfs[2] + oh), ldw<0>(wfs[2] + oh + 512), bh0, bh1);
            mfma6(a0, a1, ldw<1>(wfs[3] + oc), ldw<1>(wfs[3] + oc + 512), cc0, cc1);
            mfma6(a0, a1, ldw<1>(wfs[3] + oh), ldw<1>(wfs[3] + oh + 512), ch0, ch1);
        }
        rwrite1(arena, wave, lane, ac0, ac1, ah0, ah1);
        __syncthreads();
        if (tid < 256) {
            float cs, hs; rsum1(arena, idx, cs, hs);
            s2v = s1v + sigf(cs) * (fmaxf(hs, 0.f) - s1v);
            fstore(FAS2, offp, s2v);
        }
        __syncthreads();
        if (tid == 0) publish(FLG(3) + cg, t + 1);
        rwrite1(arena, wave, lane, bc0, bc1, bh0, bh1);
        __syncthreads();
        if (tid < 256) {
            float cs, hs; rsum1(arena, idx, cs, hs);
            s3v = s1v + sigf(cs) * (fmaxf(hs, 0.f) - s1v);
            fstore(FAS3, offp, s3v);
        }
        __syncthreads();
        if (tid == 0) publish(FLG(4) + cg, t + 1);
        rwrite1(arena, wave, lane, cc0, cc1, ch0, ch1);
        __syncthreads();
        if (tid < 256) {
            float cs, hs; rsum1(arena, idx, cs, hs);
            float s4v = s1v + sigf(cs) * (hs - s1v);
            runsum += s2v + s3v + s4v;
        }
        __syncthreads();

        // ========== L4: s5 = comb(s2,Ws4), s7 = comb(s3,Ws6)  (NT) ===========
        if (wave == 7) { pollw<0>(FLG(3), t + 1, lane); pollw<0>(FLG(4), t + 1, lane); }
        __syncthreads();
        {
            f32x4 xc0 = {}, xc1 = {}, xh0 = {}, xh1 = {};
            f32x4 yc0 = {}, yc1 = {}, yh0 = {}, yh1 = {};
            #pragma unroll
            for (int i = 0; i < 4; ++i) {
                const int ks = wave * 4 + i;
                const size_t oc = ((size_t)cg * 32 + ks) * 1024 + lane8;
                const size_t oh = ((size_t)(cg + 64) * 32 + ks) * 1024 + lane8;
                half8 a0, a1;
                aload(FAS2, ks, lane, a0, a1);
                mfma6(a0, a1, ldw<1>(wfs[4] + oc), ldw<1>(wfs[4] + oc + 512), xc0, xc1);
                mfma6(a0, a1, ldw<1>(wfs[4] + oh), ldw<1>(wfs[4] + oh + 512), xh0, xh1);
                aload(FAS3, ks, lane, a0, a1);
                mfma6(a0, a1, ldw<1>(wfs[6] + oc), ldw<1>(wfs[6] + oc + 512), yc0, yc1);
                mfma6(a0, a1, ldw<1>(wfs[6] + oh), ldw<1>(wfs[6] + oh + 512), yh0, yh1);
            }
            rwrite1(arena, wave, lane, xc0, xc1, xh0, xh1);
            __syncthreads();
            if (tid < 256) {
                float cs, hs; rsum1(arena, idx, cs, hs);
                s5v = s2v + sigf(cs) * (tanhf(hs) - s2v);
                fstore(FAS5, offp, s5v);
            }
            __syncthreads();
            if (tid == 0) publish(FLG(5) + cg, t + 1);
            rwrite1(arena, wave, lane, yc0, yc1, yh0, yh1);
            __syncthreads();
            if (tid < 256) {
                float cs, hs; rsum1(arena, idx, cs, hs);
                float s7v = s3v + sigf(cs) * (tanhf(hs) - s3v);
                runsum += s5v + s7v;
            }
            __syncthreads();
        }

        // ========== L5: s6,s8 from s5 + mean -> out[t], publish H ============
        if (wave == 7) pollw<0>(FLG(5), t + 1, lane);
        __syncthreads();
        {
            f32x4 xc0 = {}, xc1 = {}, xh0 = {}, xh1 = {};
            f32x4 yc0 = {}, yc1 = {}, yh0 = {}, yh1 = {};
            #pragma unroll
            for (int i = 0; i < 4; ++i) {
                const int ks = wave * 4 + i;
                const size_t oc = ((size_t)cg * 32 + ks) * 1024 + lane8;
                const size_t oh = ((size_t)(cg + 64) * 32 + ks) * 1024 + lane8;
                half8 a0, a1; aload(FAS5, ks, lane, a0, a1);
                mfma6(a0, a1, ldw<1>(wfs[5] + oc), ldw<1>(wfs[5] + oc + 512), xc0, xc1);
                mfma6(a0, a1, ldw<1>(wfs[5] + oh), ldw<1>(wfs[5] + oh + 512), xh0, xh1);
                mfma6(a0, a1, ldw<1>(wfs[7] + oc), ldw<1>(wfs[7] + oc + 512), yc0, yc1);
                mfma6(a0, a1, ldw<1>(wfs[7] + oh), ldw<1>(wfs[7] + oh + 512), yh0, yh1);
            }
            rwrite1(arena, wave, lane, xc0, xc1, xh0, xh1);
            __syncthreads();
            float c6 = 0.f, h6 = 0.f;
            if (tid < 256) rsum1(arena, idx, c6, h6);
            __syncthreads();
            rwrite1(arena, wave, lane, yc0, yc1, yh0, yh1);
            __syncthreads();
            if (tid < 256) {
                float c8, h8; rsum1(arena, idx, c8, h8);
                float s6 = s5v + sigf(c6) * (sigf(h6) - s5v);
                float s8 = s5v + sigf(c8) * (fmaxf(h8, 0.f) - s5v);
                float v = 0.125f * (runsum + s6 + s8);
                p.out[(size_t)t * 65536 + opos] = v;
                fstore(FAH, offp, v);
                hprev = v;
            }
            __syncthreads();
            if (tid == 0) publish(FLG(0) + cg, t + 2);
        }
    }
    #undef FLG
}

// ---------------------------------- host -------------------------------------
extern "C" void kernel_launch(void* const* d_in, const int* in_sizes, int n_in,
                              void* d_out, int out_size, void* d_ws, size_t ws_size,
                              hipStream_t stream) {
    (void)in_sizes; (void)n_in; (void)out_size; (void)ws_size;
    const float* inputs = (const float*)d_in[0];
    const float* hidden = (const float*)d_in[1];
    const float* W0     = (const float*)d_in[2];
    const float* Ws     = (const float*)d_in[3];
    float* out = (float*)d_out;

    char* base = (char*)d_ws;
    unsigned short* wf = (unsigned short*)base;
    char* fa = base + WF_BYTES;
    unsigned* flags = (unsigned*)(fa + FA_BYTES);

    initk<<<64, 256, 0, stream>>>(hidden, fa, flags);
    preconv<<<10240, 256, 0, stream>>>(Pre{W0, Ws, wf});

    PK pk{inputs, hidden, wf, fa, flags, out};
    void* args[] = {&pk};
    if (hipLaunchCooperativeKernel((void*)persist, dim3(256), dim3(512), args, 0, stream) != hipSuccess)
        persist<<<256, 512, 0, stream>>>(pk);
}

// Round 6
// 13611.429 us; speedup vs baseline: 2.0791x; 1.7490x over previous
//
#include <hip/hip_runtime.h>
#include <math.h>

// DARTS recurrent cell on MI355X — persistent cooperative kernel, v6.
// v5 -> v6 (single variable): remove ALL cache-wide fences from steady state.
//  - publishes: packed 4B limb-interleaved relaxed agent stores (sc1, LLC
//    write-through, NO buffer_wbl2), __syncthreads drains vmcnt, then a
//    RELAXED flag store (v5 used RELEASE -> wbl2 per publish, 192/XCD/step).
//  - exactly ONE acquire (buffer_inv) per step, at the L1 poll (A-frag
//    staleness cover). All other polls relaxed.
//  - NT hints dropped (let LLC retain the weight stream).

typedef __attribute__((ext_vector_type(8))) _Float16 half8;
typedef __attribute__((ext_vector_type(4))) float f32x4;
typedef __attribute__((ext_vector_type(4))) unsigned int u32x4;
typedef __attribute__((ext_vector_type(8))) unsigned short us8;

#define NH 1024
#define SCALE 2048.f
#define INVS  (1.f/2048.f)
#define WF_BYTES 83886080ull
#define FA_BYTES 1572864ull        // 6 tensors x 4 rt x 64 KB
#define T_STEPS  256

__device__ __forceinline__ float sigf(float x){ return 1.f/(1.f+__expf(-x)); }
__device__ __forceinline__ void limbs2(float x, _Float16& a, _Float16& b){
    a = (_Float16)x; b = (_Float16)((x - (float)a)*SCALE);
}

// ---------------- weight pre-swizzle (identical to v4/v5, proven) ------------
struct Pre { const float* W0; const float* Ws; unsigned short* wf; };

__global__ __launch_bounds__(256) void preconv(Pre d) {
    int gid  = blockIdx.x * 4 + (threadIdx.x >> 6);
    int lane = threadIdx.x & 63;
    const float* W; unsigned short* dst; int nks, cg, ks;
    if (gid < 8192) {
        W = d.W0; dst = d.wf; nks = 64; cg = gid >> 6; ks = gid & 63;
    } else {
        int g = gid - 8192; int mm = g >> 12; int wi = g & 4095;
        W   = d.Ws + (size_t)mm * (1024 * 2048);
        dst = d.wf + 8388608ull + (size_t)mm * 4194304ull;
        nks = 32; cg = wi >> 5; ks = wi & 31;
    }
    int c  = cg * 16 + (lane & 15);
    int kb = ks * 32 + (lane >> 4) * 8;
    half8 h0, h1;
    #pragma unroll
    for (int j = 0; j < 8; ++j) {
        _Float16 p, q; limbs2(W[(size_t)(kb + j) * 2048 + c], p, q);
        h0[j] = p; h1[j] = q;
    }
    unsigned short* o = dst + ((size_t)cg * nks + ks) * 1024 + lane * 8;
    *(half8*)o         = h0;
    *(half8*)(o + 512) = h1;
}

// -------- init: hidden -> interleaved H frag plane; flag init ----------------
__global__ __launch_bounds__(256) void initk(const float* hidden, char* fa, unsigned* flags) {
    int gid = blockIdx.x * 256 + threadIdx.x;        // 0..16383
    if (gid < 1536) flags[gid] = (gid < 256) ? 1u : 0u;   // H published once
    #pragma unroll
    for (int e = 0; e < 4; ++e) {
        int i = gid * 4 + e;
        int row = i >> 10, col = i & 1023;
        int rt = row >> 4, rowf = row & 15;
        int ksp = col >> 5, kin = col & 31;
        int lanep = (kin >> 3) * 16 + rowf;
        size_t off = (size_t)rt * 65536 + ((size_t)ksp * 64 + lanep) * 32 + (kin & 7) * 4;
        _Float16 u0, u1; limbs2(hidden[i], u0, u1);
        unsigned pk = (unsigned)__builtin_bit_cast(unsigned short, u0) |
                      ((unsigned)__builtin_bit_cast(unsigned short, u1) << 16);
        *(unsigned*)(fa + off) = pk;
    }
}

// ------------------------------ device helpers -------------------------------
// interleaved frag: per (ks,lane) 32 B = 8 elems x {limb0,limb1} 2+2 B
__device__ __forceinline__ void aload(const char* fa, int ks, int lane, half8& a0, half8& a1) {
    const char* p = fa + ((size_t)ks * 64 + lane) * 32;
    us8 q0 = *(const us8*)p;
    us8 q1 = *(const us8*)(p + 16);
    a0 = __builtin_bit_cast(half8, __builtin_shufflevector(q0, q1, 0,2,4,6,8,10,12,14));
    a1 = __builtin_bit_cast(half8, __builtin_shufflevector(q0, q1, 1,3,5,7,9,11,13,15));
}
__device__ __forceinline__ half8 ldw(const unsigned short* p) { return *(const half8*)p; }
__device__ __forceinline__ void mfma6(half8 a0, half8 a1, half8 w0, half8 w1,
                                      f32x4& x0, f32x4& x1) {
    x0 = __builtin_amdgcn_mfma_f32_16x16x32_f16(a0, w0, x0, 0, 0, 0);
    x1 = __builtin_amdgcn_mfma_f32_16x16x32_f16(a0, w1, x1, 0, 0, 0);
    x1 = __builtin_amdgcn_mfma_f32_16x16x32_f16(a1, w0, x1, 0, 0, 0);
}
__device__ __forceinline__ void rwrite1(float* arena, int wave, int lane,
        f32x4 c0, f32x4 c1, f32x4 h0, f32x4 h1) {
    float* b = arena + wave * 512;
    #pragma unroll
    for (int r = 0; r < 4; ++r) {
        b[lane * 4 + r]       = c0[r] + c1[r] * INVS;
        b[256 + lane * 4 + r] = h0[r] + h1[r] * INVS;
    }
}
__device__ __forceinline__ void rsum1(const float* arena, int idx, float& cs, float& hs) {
    float c = 0.f, h = 0.f;
    #pragma unroll
    for (int w = 0; w < 8; ++w) {
        c += arena[w * 512 + idx];
        h += arena[w * 512 + 256 + idx];
    }
    cs = c; hs = h;
}
// fence-free publish store: packed limbs, relaxed agent scope (sc1 -> LLC)
__device__ __forceinline__ void fstore(char* fa, int offp, float v) {
    _Float16 u0, u1; limbs2(v, u0, u1);
    unsigned pk = (unsigned)__builtin_bit_cast(unsigned short, u0) |
                  ((unsigned)__builtin_bit_cast(unsigned short, u1) << 16);
    __hip_atomic_store((unsigned*)(fa + offp), pk, __ATOMIC_RELAXED, __HIP_MEMORY_SCOPE_AGENT);
}
template<int ACQ>
__device__ __forceinline__ void pollw(unsigned* f, unsigned tgt, int lane) {
    unsigned v = __hip_atomic_load(f + lane, __ATOMIC_RELAXED, __HIP_MEMORY_SCOPE_AGENT);
    while (__ballot(v < tgt)) {
        __builtin_amdgcn_s_sleep(8);
        v = __hip_atomic_load(f + lane, __ATOMIC_RELAXED, __HIP_MEMORY_SCOPE_AGENT);
    }
    if (ACQ)
        (void)__hip_atomic_load(f, __ATOMIC_ACQUIRE, __HIP_MEMORY_SCOPE_AGENT);
}
// relaxed flag store (prior frag stores drained by the preceding __syncthreads)
__device__ __forceinline__ void publish(unsigned* slot, unsigned v) {
    __hip_atomic_store(slot, v, __ATOMIC_RELAXED, __HIP_MEMORY_SCOPE_AGENT);
}

// ------------------------------ persistent kernel ----------------------------
struct PK {
    const float* x; const float* hidden;
    const unsigned short* wf;
    char* fa; unsigned* flags; float* out;
};

__global__ __launch_bounds__(512, 2) void persist(PK p) {
    __shared__ unsigned short slab[65536];   // 128 KB: W0h frags
    __shared__ float arena[4096];            // 16 KB reduce arena

    const int tid  = threadIdx.x;
    const int wave = tid >> 6, lane = tid & 63;
    const int l15 = lane & 15, lg = lane >> 4;
    const int lane8 = lane * 8, lg8 = lg * 8;
    const int bx = blockIdx.x;
    const int cg = (bx & 7) * 8 + ((bx >> 3) & 7);   // same cg set -> same XCD
    const int rt = bx >> 6;

    const unsigned short* wf0 = p.wf;
    const unsigned short* wfs[8];
    #pragma unroll
    for (int i = 0; i < 8; ++i) wfs[i] = p.wf + 8388608ull + (size_t)i * 4194304ull;

    char* FAH  = p.fa + (size_t)(0 * 4 + rt) * 65536;
    char* FAS0 = p.fa + (size_t)(1 * 4 + rt) * 65536;
    char* FAS1 = p.fa + (size_t)(2 * 4 + rt) * 65536;
    char* FAS2 = p.fa + (size_t)(3 * 4 + rt) * 65536;
    char* FAS3 = p.fa + (size_t)(4 * 4 + rt) * 65536;
    char* FAS5 = p.fa + (size_t)(5 * 4 + rt) * 65536;
    #define FLG(tn) (p.flags + ((tn) * 4 + rt) * 64)

    // ---- fill W0h LDS slab (once) ----
    {
        const u32x4* sc = (const u32x4*)(wf0 + ((size_t)cg * 64 + 32) * 1024);
        const u32x4* sh = (const u32x4*)(wf0 + ((size_t)(cg + 64) * 64 + 32) * 1024);
        u32x4* dst = (u32x4*)slab;
        for (int i = tid; i < 4096; i += 512) { dst[i] = sc[i]; dst[4096 + i] = sh[i]; }
    }

    // epilogue-thread fixed position (tid < 256)
    const int rowf = tid >> 4, colf = tid & 15;
    const size_t opos = (size_t)(rt * 16 + rowf) * NH + cg * 16 + colf;
    const int idx = colf * 4 + (rowf >> 2) * 64 + (rowf & 3);
    int offp;
    {
        int col = cg * 16 + colf;
        int ksp = col >> 5, kin = col & 31;
        int lanep = (kin >> 3) * 16 + rowf;
        offp = (ksp * 64 + lanep) * 32 + (kin & 7) * 4;
    }
    float hprev = 0.f, s0v = 0.f, s1v = 0.f, s2v = 0.f, s3v = 0.f, s5v = 0.f, runsum = 0.f;
    if (tid < 256) hprev = p.hidden[opos];
    const int xrow = rt * 16 + l15;
    __syncthreads();

    for (int t = 0; t < T_STEPS; ++t) {
        const float* xt = p.x + (size_t)t * 65536;

        // ========== L1: s0 = comb(h, [x|h] @ W0)  (the step's ONE acquire) ===
        if (wave == 7) pollw<1>(FLG(0), t + 1, lane);
        __syncthreads();
        {
            f32x4 c0 = {}, c1 = {}, h0 = {}, h1 = {};
            #pragma unroll
            for (int i = 0; i < 8; ++i) {
                const int ks = wave * 8 + i;
                half8 a0, a1, w0c, w1c, w0h, w1h;
                if (ks < 32) {                          // x-half: convert
                    const float* xp = xt + (size_t)xrow * NH + ks * 32 + lg8;
                    float4 v0 = *(const float4*)xp, v1 = *(const float4*)(xp + 4);
                    float fv[8] = {v0.x, v0.y, v0.z, v0.w, v1.x, v1.y, v1.z, v1.w};
                    #pragma unroll
                    for (int j = 0; j < 8; ++j) { _Float16 u, w2; limbs2(fv[j], u, w2); a0[j] = u; a1[j] = w2; }
                    const unsigned short* pc = wf0 + ((size_t)cg * 64 + ks) * 1024 + lane8;
                    const unsigned short* ph = wf0 + ((size_t)(cg + 64) * 64 + ks) * 1024 + lane8;
                    w0c = ldw(pc); w1c = ldw(pc + 512);
                    w0h = ldw(ph); w1h = ldw(ph + 512);
                } else {                                // h-half: FA + LDS slab
                    aload(FAH, ks - 32, lane, a0, a1);
                    const unsigned short* pc = &slab[(ks - 32) * 1024 + lane8];
                    const unsigned short* ph = &slab[(ks) * 1024 + lane8];
                    w0c = *(const half8*)pc; w1c = *(const half8*)(pc + 512);
                    w0h = *(const half8*)ph; w1h = *(const half8*)(ph + 512);
                }
                mfma6(a0, a1, w0c, w1c, c0, c1);
                mfma6(a0, a1, w0h, w1h, h0, h1);
            }
            rwrite1(arena, wave, lane, c0, c1, h0, h1);
        }
        __syncthreads();
        if (tid < 256) {
            float cs, hs; rsum1(arena, idx, cs, hs);
            s0v = hprev + sigf(cs) * (tanhf(hs) - hprev);
            fstore(FAS0, offp, s0v);
        }
        __syncthreads();
        if (tid == 0) publish(FLG(1) + cg, t + 1);

        // ========== L2: s1 = comb(s0, s0 @ Ws0) ==============================
        if (wave == 7) pollw<0>(FLG(1), t + 1, lane);
        __syncthreads();
        {
            f32x4 c0 = {}, c1 = {}, h0 = {}, h1 = {};
            #pragma unroll
            for (int i = 0; i < 4; ++i) {
                const int ks = wave * 4 + i;
                half8 a0, a1; aload(FAS0, ks, lane, a0, a1);
                const unsigned short* pc = wfs[0] + ((size_t)cg * 32 + ks) * 1024 + lane8;
                const unsigned short* ph = wfs[0] + ((size_t)(cg + 64) * 32 + ks) * 1024 + lane8;
                mfma6(a0, a1, ldw(pc), ldw(pc + 512), c0, c1);
                mfma6(a0, a1, ldw(ph), ldw(ph + 512), h0, h1);
            }
            rwrite1(arena, wave, lane, c0, c1, h0, h1);
        }
        __syncthreads();
        if (tid < 256) {
            float cs, hs; rsum1(arena, idx, cs, hs);
            s1v = s0v + sigf(cs) * (sigf(hs) - s0v);
            fstore(FAS1, offp, s1v);
            runsum = s1v;
        }
        __syncthreads();
        if (tid == 0) publish(FLG(2) + cg, t + 1);

        // ========== L3: s2,s3,s4 from s1 (Ws1..3) ============================
        if (wave == 7) pollw<0>(FLG(2), t + 1, lane);
        __syncthreads();
        f32x4 ac0 = {}, ac1 = {}, ah0 = {}, ah1 = {};
        f32x4 bc0 = {}, bc1 = {}, bh0 = {}, bh1 = {};
        f32x4 cc0 = {}, cc1 = {}, ch0 = {}, ch1 = {};
        #pragma unroll
        for (int i = 0; i < 4; ++i) {
            const int ks = wave * 4 + i;
            half8 a0, a1; aload(FAS1, ks, lane, a0, a1);
            const size_t oc = ((size_t)cg * 32 + ks) * 1024 + lane8;
            const size_t oh = ((size_t)(cg + 64) * 32 + ks) * 1024 + lane8;
            mfma6(a0, a1, ldw(wfs[1] + oc), ldw(wfs[1] + oc + 512), ac0, ac1);
            mfma6(a0, a1, ldw(wfs[1] + oh), ldw(wfs[1] + oh + 512), ah0, ah1);
            mfma6(a0, a1, ldw(wfs[2] + oc), ldw(wfs[2] + oc + 512), bc0, bc1);
            mfma6(a0, a1, ldw(wfs[2] + oh), ldw(wfs[2] + oh + 512), bh0, bh1);
            mfma6(a0, a1, ldw(wfs[3] + oc), ldw(wfs[3] + oc + 512), cc0, cc1);
            mfma6(a0, a1, ldw(wfs[3] + oh), ldw(wfs[3] + oh + 512), ch0, ch1);
        }
        rwrite1(arena, wave, lane, ac0, ac1, ah0, ah1);
        __syncthreads();
        if (tid < 256) {
            float cs, hs; rsum1(arena, idx, cs, hs);
            s2v = s1v + sigf(cs) * (fmaxf(hs, 0.f) - s1v);
            fstore(FAS2, offp, s2v);
        }
        __syncthreads();
        if (tid == 0) publish(FLG(3) + cg, t + 1);
        rwrite1(arena, wave, lane, bc0, bc1, bh0, bh1);
        __syncthreads();
        if (tid < 256) {
            float cs, hs; rsum1(arena, idx, cs, hs);
            s3v = s1v + sigf(cs) * (fmaxf(hs, 0.f) - s1v);
            fstore(FAS3, offp, s3v);
        }
        __syncthreads();
        if (tid == 0) publish(FLG(4) + cg, t + 1);
        rwrite1(arena, wave, lane, cc0, cc1, ch0, ch1);
        __syncthreads();
        if (tid < 256) {
            float cs, hs; rsum1(arena, idx, cs, hs);
            float s4v = s1v + sigf(cs) * (hs - s1v);
            runsum += s2v + s3v + s4v;
        }
        __syncthreads();

        // ========== L4: s5 = comb(s2,Ws4), s7 = comb(s3,Ws6) =================
        if (wave == 7) { pollw<0>(FLG(3), t + 1, lane); pollw<0>(FLG(4), t + 1, lane); }
        __syncthreads();
        {
            f32x4 xc0 = {}, xc1 = {}, xh0 = {}, xh1 = {};
            f32x4 yc0 = {}, yc1 = {}, yh0 = {}, yh1 = {};
            #pragma unroll
            for (int i = 0; i < 4; ++i) {
                const int ks = wave * 4 + i;
                const size_t oc = ((size_t)cg * 32 + ks) * 1024 + lane8;
                const size_t oh = ((size_t)(cg + 64) * 32 + ks) * 1024 + lane8;
                half8 a0, a1;
                aload(FAS2, ks, lane, a0, a1);
                mfma6(a0, a1, ldw(wfs[4] + oc), ldw(wfs[4] + oc + 512), xc0, xc1);
                mfma6(a0, a1, ldw(wfs[4] + oh), ldw(wfs[4] + oh + 512), xh0, xh1);
                aload(FAS3, ks, lane, a0, a1);
                mfma6(a0, a1, ldw(wfs[6] + oc), ldw(wfs[6] + oc + 512), yc0, yc1);
                mfma6(a0, a1, ldw(wfs[6] + oh), ldw(wfs[6] + oh + 512), yh0, yh1);
            }
            rwrite1(arena, wave, lane, xc0, xc1, xh0, xh1);
            __syncthreads();
            if (tid < 256) {
                float cs, hs; rsum1(arena, idx, cs, hs);
                s5v = s2v + sigf(cs) * (tanhf(hs) - s2v);
                fstore(FAS5, offp, s5v);
            }
            __syncthreads();
            if (tid == 0) publish(FLG(5) + cg, t + 1);
            rwrite1(arena, wave, lane, yc0, yc1, yh0, yh1);
            __syncthreads();
            if (tid < 256) {
                float cs, hs; rsum1(arena, idx, cs, hs);
                float s7v = s3v + sigf(cs) * (tanhf(hs) - s3v);
                runsum += s5v + s7v;
            }
            __syncthreads();
        }

        // ========== L5: s6,s8 from s5 + mean -> out[t], publish H ============
        if (wave == 7) pollw<0>(FLG(5), t + 1, lane);
        __syncthreads();
        {
            f32x4 xc0 = {}, xc1 = {}, xh0 = {}, xh1 = {};
            f32x4 yc0 = {}, yc1 = {}, yh0 = {}, yh1 = {};
            #pragma unroll
            for (int i = 0; i < 4; ++i) {
                const int ks = wave * 4 + i;
                const size_t oc = ((size_t)cg * 32 + ks) * 1024 + lane8;
                const size_t oh = ((size_t)(cg + 64) * 32 + ks) * 1024 + lane8;
                half8 a0, a1; aload(FAS5, ks, lane, a0, a1);
                mfma6(a0, a1, ldw(wfs[5] + oc), ldw(wfs[5] + oc + 512), xc0, xc1);
                mfma6(a0, a1, ldw(wfs[5] + oh), ldw(wfs[5] + oh + 512), xh0, xh1);
                mfma6(a0, a1, ldw(wfs[7] + oc), ldw(wfs[7] + oc + 512), yc0, yc1);
                mfma6(a0, a1, ldw(wfs[7] + oh), ldw(wfs[7] + oh + 512), yh0, yh1);
            }
            rwrite1(arena, wave, lane, xc0, xc1, xh0, xh1);
            __syncthreads();
            float c6 = 0.f, h6 = 0.f;
            if (tid < 256) rsum1(arena, idx, c6, h6);
            __syncthreads();
            rwrite1(arena, wave, lane, yc0, yc1, yh0, yh1);
            __syncthreads();
            if (tid < 256) {
                float c8, h8; rsum1(arena, idx, c8, h8);
                float s6 = s5v + sigf(c6) * (sigf(h6) - s5v);
                float s8 = s5v + sigf(c8) * (fmaxf(h8, 0.f) - s5v);
                float v = 0.125f * (runsum + s6 + s8);
                p.out[(size_t)t * 65536 + opos] = v;
                fstore(FAH, offp, v);
                hprev = v;
            }
            __syncthreads();
            if (tid == 0) publish(FLG(0) + cg, t + 2);
        }
    }
    #undef FLG
}

// ---------------------------------- host -------------------------------------
extern "C" void kernel_launch(void* const* d_in, const int* in_sizes, int n_in,
                              void* d_out, int out_size, void* d_ws, size_t ws_size,
                              hipStream_t stream) {
    (void)in_sizes; (void)n_in; (void)out_size; (void)ws_size;
    const float* inputs = (const float*)d_in[0];
    const float* hidden = (const float*)d_in[1];
    const float* W0     = (const float*)d_in[2];
    const float* Ws     = (const float*)d_in[3];
    float* out = (float*)d_out;

    char* base = (char*)d_ws;
    unsigned short* wf = (unsigned short*)base;
    char* fa = base + WF_BYTES;
    unsigned* flags = (unsigned*)(fa + FA_BYTES);

    initk<<<64, 256, 0, stream>>>(hidden, fa, flags);
    preconv<<<10240, 256, 0, stream>>>(Pre{W0, Ws, wf});

    PK pk{inputs, hidden, wf, fa, flags, out};
    void* args[] = {&pk};
    if (hipLaunchCooperativeKernel((void*)persist, dim3(256), dim3(512), args, 0, stream) != hipSuccess)
        persist<<<256, 512, 0, stream>>>(pk);
}

// Round 7
// 9705.830 us; speedup vs baseline: 2.9158x; 1.4024x over previous
//
#include <hip/hip_runtime.h>
#include <math.h>

// DARTS recurrent cell on MI355X — persistent cooperative kernel, v7.
// v6 -> v7: deep poll-overlapped weight prefetch (fix latency-bound stream).
//  - each level batch-issues its weight frags (16/wave/matrix) BEFORE the
//    level's flag poll: poll latency = load landing time; 16-32 KB in flight
//    per wave vs ~6 KB (v6 measured ~3.6 KB/CU -> 1.3 TB/s).
//  - L1: x-half of W0 (h-independent) prefetched AND computed before the H
//    poll; h-half uses the LDS slab + FA.
//  - L3 pipelines Ws1/Ws2 (pre-poll) and Ws3 (under Ws1 MFMAs).
//  - sync semantics identical to v6 (relaxed publishes, ONE acquire/step).

typedef __attribute__((ext_vector_type(8))) _Float16 half8;
typedef __attribute__((ext_vector_type(4))) float f32x4;
typedef __attribute__((ext_vector_type(4))) unsigned int u32x4;
typedef __attribute__((ext_vector_type(8))) unsigned short us8;

#define NH 1024
#define SCALE 2048.f
#define INVS  (1.f/2048.f)
#define WF_BYTES 83886080ull
#define FA_BYTES 1572864ull
#define T_STEPS  256

__device__ __forceinline__ float sigf(float x){ return 1.f/(1.f+__expf(-x)); }
__device__ __forceinline__ void limbs2(float x, _Float16& a, _Float16& b){
    a = (_Float16)x; b = (_Float16)((x - (float)a)*SCALE);
}

// ---------------- weight pre-swizzle (identical to v4-v6, proven) ------------
struct Pre { const float* W0; const float* Ws; unsigned short* wf; };

__global__ __launch_bounds__(256) void preconv(Pre d) {
    int gid  = blockIdx.x * 4 + (threadIdx.x >> 6);
    int lane = threadIdx.x & 63;
    const float* W; unsigned short* dst; int nks, cg, ks;
    if (gid < 8192) {
        W = d.W0; dst = d.wf; nks = 64; cg = gid >> 6; ks = gid & 63;
    } else {
        int g = gid - 8192; int mm = g >> 12; int wi = g & 4095;
        W   = d.Ws + (size_t)mm * (1024 * 2048);
        dst = d.wf + 8388608ull + (size_t)mm * 4194304ull;
        nks = 32; cg = wi >> 5; ks = wi & 31;
    }
    int c  = cg * 16 + (lane & 15);
    int kb = ks * 32 + (lane >> 4) * 8;
    half8 h0, h1;
    #pragma unroll
    for (int j = 0; j < 8; ++j) {
        _Float16 p, q; limbs2(W[(size_t)(kb + j) * 2048 + c], p, q);
        h0[j] = p; h1[j] = q;
    }
    unsigned short* o = dst + ((size_t)cg * nks + ks) * 1024 + lane * 8;
    *(half8*)o         = h0;
    *(half8*)(o + 512) = h1;
}

// -------- init: hidden -> interleaved H frag plane; flag init ----------------
__global__ __launch_bounds__(256) void initk(const float* hidden, char* fa, unsigned* flags) {
    int gid = blockIdx.x * 256 + threadIdx.x;
    if (gid < 1536) flags[gid] = (gid < 256) ? 1u : 0u;
    #pragma unroll
    for (int e = 0; e < 4; ++e) {
        int i = gid * 4 + e;
        int row = i >> 10, col = i & 1023;
        int rt = row >> 4, rowf = row & 15;
        int ksp = col >> 5, kin = col & 31;
        int lanep = (kin >> 3) * 16 + rowf;
        size_t off = (size_t)rt * 65536 + ((size_t)ksp * 64 + lanep) * 32 + (kin & 7) * 4;
        _Float16 u0, u1; limbs2(hidden[i], u0, u1);
        unsigned pk = (unsigned)__builtin_bit_cast(unsigned short, u0) |
                      ((unsigned)__builtin_bit_cast(unsigned short, u1) << 16);
        *(unsigned*)(fa + off) = pk;
    }
}

// ------------------------------ device helpers -------------------------------
__device__ __forceinline__ void aload(const char* fa, int ks, int lane, half8& a0, half8& a1) {
    const char* p = fa + ((size_t)ks * 64 + lane) * 32;
    us8 q0 = *(const us8*)p;
    us8 q1 = *(const us8*)(p + 16);
    a0 = __builtin_bit_cast(half8, __builtin_shufflevector(q0, q1, 0,2,4,6,8,10,12,14));
    a1 = __builtin_bit_cast(half8, __builtin_shufflevector(q0, q1, 1,3,5,7,9,11,13,15));
}
__device__ __forceinline__ half8 ldw(const unsigned short* p) { return *(const half8*)p; }
__device__ __forceinline__ void mfma6(half8 a0, half8 a1, half8 w0, half8 w1,
                                      f32x4& x0, f32x4& x1) {
    x0 = __builtin_amdgcn_mfma_f32_16x16x32_f16(a0, w0, x0, 0, 0, 0);
    x1 = __builtin_amdgcn_mfma_f32_16x16x32_f16(a0, w1, x1, 0, 0, 0);
    x1 = __builtin_amdgcn_mfma_f32_16x16x32_f16(a1, w0, x1, 0, 0, 0);
}
__device__ __forceinline__ void rwrite1(float* arena, int wave, int lane,
        f32x4 c0, f32x4 c1, f32x4 h0, f32x4 h1) {
    float* b = arena + wave * 512;
    #pragma unroll
    for (int r = 0; r < 4; ++r) {
        b[lane * 4 + r]       = c0[r] + c1[r] * INVS;
        b[256 + lane * 4 + r] = h0[r] + h1[r] * INVS;
    }
}
__device__ __forceinline__ void rsum1(const float* arena, int idx, float& cs, float& hs) {
    float c = 0.f, h = 0.f;
    #pragma unroll
    for (int w = 0; w < 8; ++w) {
        c += arena[w * 512 + idx];
        h += arena[w * 512 + 256 + idx];
    }
    cs = c; hs = h;
}
__device__ __forceinline__ void fstore(char* fa, int offp, float v) {
    _Float16 u0, u1; limbs2(v, u0, u1);
    unsigned pk = (unsigned)__builtin_bit_cast(unsigned short, u0) |
                  ((unsigned)__builtin_bit_cast(unsigned short, u1) << 16);
    __hip_atomic_store((unsigned*)(fa + offp), pk, __ATOMIC_RELAXED, __HIP_MEMORY_SCOPE_AGENT);
}
template<int ACQ>
__device__ __forceinline__ void pollw(unsigned* f, unsigned tgt, int lane) {
    unsigned v = __hip_atomic_load(f + lane, __ATOMIC_RELAXED, __HIP_MEMORY_SCOPE_AGENT);
    while (__ballot(v < tgt)) {
        __builtin_amdgcn_s_sleep(2);
        v = __hip_atomic_load(f + lane, __ATOMIC_RELAXED, __HIP_MEMORY_SCOPE_AGENT);
    }
    if (ACQ)
        (void)__hip_atomic_load(f, __ATOMIC_ACQUIRE, __HIP_MEMORY_SCOPE_AGENT);
}
__device__ __forceinline__ void publish(unsigned* slot, unsigned v) {
    __hip_atomic_store(slot, v, __ATOMIC_RELAXED, __HIP_MEMORY_SCOPE_AGENT);
}

// ------------------------------ persistent kernel ----------------------------
struct PK {
    const float* x; const float* hidden;
    const unsigned short* wf;
    char* fa; unsigned* flags; float* out;
};

__global__ __launch_bounds__(512, 2) void persist(PK p) {
    __shared__ unsigned short slab[65536];   // 128 KB: W0h frags
    __shared__ float arena[4096];            // 16 KB reduce arena

    const int tid  = threadIdx.x;
    const int wave = tid >> 6, lane = tid & 63;
    const int l15 = lane & 15, lg = lane >> 4;
    const int lane8 = lane * 8, lg8 = lg * 8;
    const int bx = blockIdx.x;
    const int cg = (bx & 7) * 8 + ((bx >> 3) & 7);
    const int rt = bx >> 6;

    const unsigned short* wf0 = p.wf;
    const unsigned short* wfs[8];
    #pragma unroll
    for (int i = 0; i < 8; ++i) wfs[i] = p.wf + 8388608ull + (size_t)i * 4194304ull;

    char* FAH  = p.fa + (size_t)(0 * 4 + rt) * 65536;
    char* FAS0 = p.fa + (size_t)(1 * 4 + rt) * 65536;
    char* FAS1 = p.fa + (size_t)(2 * 4 + rt) * 65536;
    char* FAS2 = p.fa + (size_t)(3 * 4 + rt) * 65536;
    char* FAS3 = p.fa + (size_t)(4 * 4 + rt) * 65536;
    char* FAS5 = p.fa + (size_t)(5 * 4 + rt) * 65536;
    #define FLG(tn) (p.flags + ((tn) * 4 + rt) * 64)

    // prefetch 16 weight frags (one matrix, this wave's 4 ks) into regs
    #define PFW(dst, wfp) do { \
        _Pragma("unroll") \
        for (int _i = 0; _i < 4; ++_i) { \
            const int _ks = wave * 4 + _i; \
            const unsigned short* _pc = (wfp) + ((size_t)cg * 32 + _ks) * 1024 + lane8; \
            const unsigned short* _ph = (wfp) + ((size_t)(cg + 64) * 32 + _ks) * 1024 + lane8; \
            dst[_i*4+0] = ldw(_pc); dst[_i*4+1] = ldw(_pc + 512); \
            dst[_i*4+2] = ldw(_ph); dst[_i*4+3] = ldw(_ph + 512); } } while (0)
    #define ALD(dst0, dst1, fa) do { \
        _Pragma("unroll") \
        for (int _i = 0; _i < 4; ++_i) aload(fa, wave * 4 + _i, lane, dst0[_i], dst1[_i]); } while (0)
    #define MFM(w, a0v, a1v, X0, X1, Y0, Y1) do { \
        _Pragma("unroll") \
        for (int _i = 0; _i < 4; ++_i) { \
            mfma6(a0v[_i], a1v[_i], w[_i*4+0], w[_i*4+1], X0, X1); \
            mfma6(a0v[_i], a1v[_i], w[_i*4+2], w[_i*4+3], Y0, Y1); } } while (0)

    // ---- fill W0h LDS slab (once) ----
    {
        const u32x4* sc = (const u32x4*)(wf0 + ((size_t)cg * 64 + 32) * 1024);
        const u32x4* sh = (const u32x4*)(wf0 + ((size_t)(cg + 64) * 64 + 32) * 1024);
        u32x4* dst = (u32x4*)slab;
        for (int i = tid; i < 4096; i += 512) { dst[i] = sc[i]; dst[4096 + i] = sh[i]; }
    }

    const int rowf = tid >> 4, colf = tid & 15;
    const size_t opos = (size_t)(rt * 16 + rowf) * NH + cg * 16 + colf;
    const int idx = colf * 4 + (rowf >> 2) * 64 + (rowf & 3);
    int offp;
    {
        int col = cg * 16 + colf;
        int ksp = col >> 5, kin = col & 31;
        int lanep = (kin >> 3) * 16 + rowf;
        offp = (ksp * 64 + lanep) * 32 + (kin & 7) * 4;
    }
    float hprev = 0.f, s0v = 0.f, s1v = 0.f, s2v = 0.f, s3v = 0.f, s5v = 0.f, runsum = 0.f;
    if (tid < 256) hprev = p.hidden[opos];
    const int xrow = rt * 16 + l15;
    __syncthreads();

    for (int t = 0; t < T_STEPS; ++t) {
        const float* xt = p.x + (size_t)t * 65536;

        // ========== L1: x-part first (h-independent), poll hidden under it ===
        f32x4 c0 = {}, c1 = {}, h0 = {}, h1 = {};
        {
            half8 xw[16], xa0[4], xa1[4];
            #pragma unroll
            for (int i = 0; i < 4; ++i) {           // prefetch W0x + load x
                const int ks = wave * 4 + i;
                const unsigned short* pc = wf0 + ((size_t)cg * 64 + ks) * 1024 + lane8;
                const unsigned short* ph = wf0 + ((size_t)(cg + 64) * 64 + ks) * 1024 + lane8;
                xw[i*4+0] = ldw(pc); xw[i*4+1] = ldw(pc + 512);
                xw[i*4+2] = ldw(ph); xw[i*4+3] = ldw(ph + 512);
                const float* xp = xt + (size_t)xrow * NH + ks * 32 + lg8;
                float4 v0 = *(const float4*)xp, v1 = *(const float4*)(xp + 4);
                float fv[8] = {v0.x, v0.y, v0.z, v0.w, v1.x, v1.y, v1.z, v1.w};
                #pragma unroll
                for (int j = 0; j < 8; ++j) { _Float16 u, w2; limbs2(fv[j], u, w2); xa0[i][j] = u; xa1[i][j] = w2; }
            }
            if (wave == 7) pollw<1>(FLG(0), t + 1, lane);     // the step's ONE acquire
            MFM(xw, xa0, xa1, c0, c1, h0, h1);
        }
        __syncthreads();                            // acquire ordered before FAH reads
        {
            half8 ha0[4], ha1[4];
            ALD(ha0, ha1, FAH);
            #pragma unroll
            for (int i = 0; i < 4; ++i) {           // W0h from LDS slab
                const int kc = wave * 4 + i;
                const unsigned short* pc = &slab[kc * 1024 + lane8];
                const unsigned short* ph = &slab[(kc + 32) * 1024 + lane8];
                mfma6(ha0[i], ha1[i], *(const half8*)pc, *(const half8*)(pc + 512), c0, c1);
                mfma6(ha0[i], ha1[i], *(const half8*)ph, *(const half8*)(ph + 512), h0, h1);
            }
            rwrite1(arena, wave, lane, c0, c1, h0, h1);
        }
        __syncthreads();
        if (tid < 256) {
            float cs, hs; rsum1(arena, idx, cs, hs);
            s0v = hprev + sigf(cs) * (tanhf(hs) - hprev);
            fstore(FAS0, offp, s0v);
        }
        __syncthreads();
        if (tid == 0) publish(FLG(1) + cg, t + 1);

        // ========== L2: s1 = comb(s0, s0 @ Ws0)  (Ws0 prefetched pre-poll) ===
        {
            half8 w0[16];
            PFW(w0, wfs[0]);
            if (wave == 7) pollw<0>(FLG(1), t + 1, lane);
            __syncthreads();
            half8 a0[4], a1[4];
            ALD(a0, a1, FAS0);
            f32x4 X0 = {}, X1 = {}, Y0 = {}, Y1 = {};
            MFM(w0, a0, a1, X0, X1, Y0, Y1);
            rwrite1(arena, wave, lane, X0, X1, Y0, Y1);
        }
        __syncthreads();
        if (tid < 256) {
            float cs, hs; rsum1(arena, idx, cs, hs);
            s1v = s0v + sigf(cs) * (sigf(hs) - s0v);
            fstore(FAS1, offp, s1v);
            runsum = s1v;
        }
        __syncthreads();
        if (tid == 0) publish(FLG(2) + cg, t + 1);

        // ========== L3: s2,s3,s4 (Ws1+Ws2 pre-poll; Ws3 under Ws1 MFMAs) =====
        {
            half8 w1[16], w2[16];
            PFW(w1, wfs[1]);
            PFW(w2, wfs[2]);
            if (wave == 7) pollw<0>(FLG(2), t + 1, lane);
            __syncthreads();
            half8 a0[4], a1[4];
            ALD(a0, a1, FAS1);
            f32x4 X0 = {}, X1 = {}, Y0 = {}, Y1 = {};
            MFM(w1, a0, a1, X0, X1, Y0, Y1);
            half8 w3[16];
            PFW(w3, wfs[3]);                        // issue under the arena dance
            rwrite1(arena, wave, lane, X0, X1, Y0, Y1);
            __syncthreads();
            if (tid < 256) {
                float cs, hs; rsum1(arena, idx, cs, hs);
                s2v = s1v + sigf(cs) * (fmaxf(hs, 0.f) - s1v);
                fstore(FAS2, offp, s2v);
            }
            __syncthreads();
            if (tid == 0) publish(FLG(3) + cg, t + 1);
            X0 = (f32x4){}; X1 = (f32x4){}; Y0 = (f32x4){}; Y1 = (f32x4){};
            MFM(w2, a0, a1, X0, X1, Y0, Y1);
            rwrite1(arena, wave, lane, X0, X1, Y0, Y1);
            __syncthreads();
            if (tid < 256) {
                float cs, hs; rsum1(arena, idx, cs, hs);
                s3v = s1v + sigf(cs) * (fmaxf(hs, 0.f) - s1v);
                fstore(FAS3, offp, s3v);
            }
            __syncthreads();
            if (tid == 0) publish(FLG(4) + cg, t + 1);
            X0 = (f32x4){}; X1 = (f32x4){}; Y0 = (f32x4){}; Y1 = (f32x4){};
            MFM(w3, a0, a1, X0, X1, Y0, Y1);
            rwrite1(arena, wave, lane, X0, X1, Y0, Y1);
            __syncthreads();
            if (tid < 256) {
                float cs, hs; rsum1(arena, idx, cs, hs);
                float s4v = s1v + sigf(cs) * (hs - s1v);
                runsum += s2v + s3v + s4v;
            }
            __syncthreads();
        }

        // ========== L4: s5 (Ws4, A=s2), s7 (Ws6, A=s3)  (both pre-poll) ======
        {
            half8 w4[16], w6[16];
            PFW(w4, wfs[4]);
            PFW(w6, wfs[6]);
            if (wave == 7) { pollw<0>(FLG(3), t + 1, lane); pollw<0>(FLG(4), t + 1, lane); }
            __syncthreads();
            half8 a0[4], a1[4], b0[4], b1[4];
            ALD(a0, a1, FAS2);
            ALD(b0, b1, FAS3);
            f32x4 X0 = {}, X1 = {}, Y0 = {}, Y1 = {};
            MFM(w4, a0, a1, X0, X1, Y0, Y1);
            f32x4 U0 = {}, U1 = {}, V0 = {}, V1 = {};
            MFM(w6, b0, b1, U0, U1, V0, V1);
            rwrite1(arena, wave, lane, X0, X1, Y0, Y1);
            __syncthreads();
            if (tid < 256) {
                float cs, hs; rsum1(arena, idx, cs, hs);
                s5v = s2v + sigf(cs) * (tanhf(hs) - s2v);
                fstore(FAS5, offp, s5v);
            }
            __syncthreads();
            if (tid == 0) publish(FLG(5) + cg, t + 1);
            rwrite1(arena, wave, lane, U0, U1, V0, V1);
            __syncthreads();
            if (tid < 256) {
                float cs, hs; rsum1(arena, idx, cs, hs);
                float s7v = s3v + sigf(cs) * (tanhf(hs) - s3v);
                runsum += s5v + s7v;
            }
            __syncthreads();
        }

        // ========== L5: s6,s8 (Ws5,Ws7, A=s5) + mean -> out[t] ===============
        {
            half8 w5[16], w7[16];
            PFW(w5, wfs[5]);
            PFW(w7, wfs[7]);
            if (wave == 7) pollw<0>(FLG(5), t + 1, lane);
            __syncthreads();
            half8 a0[4], a1[4];
            ALD(a0, a1, FAS5);
            f32x4 X0 = {}, X1 = {}, Y0 = {}, Y1 = {};
            MFM(w5, a0, a1, X0, X1, Y0, Y1);
            f32x4 U0 = {}, U1 = {}, V0 = {}, V1 = {};
            MFM(w7, a0, a1, U0, U1, V0, V1);
            rwrite1(arena, wave, lane, X0, X1, Y0, Y1);
            __syncthreads();
            float c6 = 0.f, h6 = 0.f;
            if (tid < 256) rsum1(arena, idx, c6, h6);
            __syncthreads();
            rwrite1(arena, wave, lane, U0, U1, V0, V1);
            __syncthreads();
            if (tid < 256) {
                float c8, h8; rsum1(arena, idx, c8, h8);
                float s6 = s5v + sigf(c6) * (sigf(h6) - s5v);
                float s8 = s5v + sigf(c8) * (fmaxf(h8, 0.f) - s5v);
                float v = 0.125f * (runsum + s6 + s8);
                p.out[(size_t)t * 65536 + opos] = v;
                fstore(FAH, offp, v);
                hprev = v;
            }
            __syncthreads();
            if (tid == 0) publish(FLG(0) + cg, t + 2);
        }
    }
    #undef FLG
    #undef PFW
    #undef ALD
    #undef MFM
}

// ---------------------------------- host -------------------------------------
extern "C" void kernel_launch(void* const* d_in, const int* in_sizes, int n_in,
                              void* d_out, int out_size, void* d_ws, size_t ws_size,
                              hipStream_t stream) {
    (void)in_sizes; (void)n_in; (void)out_size; (void)ws_size;
    const float* inputs = (const float*)d_in[0];
    const float* hidden = (const float*)d_in[1];
    const float* W0     = (const float*)d_in[2];
    const float* Ws     = (const float*)d_in[3];
    float* out = (float*)d_out;

    char* base = (char*)d_ws;
    unsigned short* wf = (unsigned short*)base;
    char* fa = base + WF_BYTES;
    unsigned* flags = (unsigned*)(fa + FA_BYTES);

    initk<<<64, 256, 0, stream>>>(hidden, fa, flags);
    preconv<<<10240, 256, 0, stream>>>(Pre{W0, Ws, wf});

    PK pk{inputs, hidden, wf, fa, flags, out};
    void* args[] = {&pk};
    if (hipLaunchCooperativeKernel((void*)persist, dim3(256), dim3(512), args, 0, stream) != hipSuccess)
        persist<<<256, 512, 0, stream>>>(pk);
}